// Round 1
// 6090.894 us; speedup vs baseline: 1.9505x; 1.9505x over previous
//
#include <hip/hip_runtime.h>
#include <hip/hip_bf16.h>

#define HDIM 1024
#define VDIM 512
#define TLEN 256
#define BATCH 256
#define FPDIM 2048
#define H3 3072

typedef __hip_bfloat16 bf16;
typedef __attribute__((ext_vector_type(8))) short s8v;    // 8 bf16 (4 VGPRs)
typedef __attribute__((ext_vector_type(4))) float f4v;    // MFMA C/D

__device__ __forceinline__ f4v mfma_bf16(s8v a, s8v b, f4v c) {
  return __builtin_amdgcn_mfma_f32_16x16x32_bf16(a, b, c, 0, 0, 0);
}
__device__ __forceinline__ s8v ld8(const bf16* p) { return *(const s8v*)p; }
__device__ __forceinline__ float sigf(float x) { return 1.f / (1.f + expf(-x)); }
// fp32 -> bf16 bits, RNE
__device__ __forceinline__ short f2bs(float f) {
  union { float f; unsigned u; } c; c.f = f;
  unsigned u = c.u + 0x7fff + ((c.u >> 16) & 1);
  return (short)(u >> 16);
}

// ============ one-time: fp32 [N,1024] -> bf16 MFMA-frag blob ============
// blob[((nt*32+kc)*64 + lane)*8 + j]; n = nt*16+(lane&15), k = kc*32+(lane>>4)*8+j
__global__ __launch_bounds__(256) void shuffle_w(const float* __restrict__ src,
                                                 bf16* __restrict__ dst, int ngroups) {
  int g = blockIdx.x * 256 + threadIdx.x;
  if (g >= ngroups) return;
  int lane = g & 63, kc = (g >> 6) & 31, nt = g >> 11;
  int n = nt * 16 + (lane & 15);
  int k = kc * 32 + ((lane >> 4) << 3);
  const float* s = src + (size_t)n * HDIM + k;
  short* d = (short*)dst + (size_t)g * 8;
  s8v v;
#pragma unroll
  for (int j = 0; j < 8; ++j) v[j] = f2bs(s[j]);
  *(s8v*)d = v;
}

// ============ one-time fp32 tile GEMM: C = [relu](A[M,K] @ W[N,K]^T + bias [+bias2 if n<lim]) ============
struct GemmArgs {
  const float* A; const float* W; const float* bias; const float* bias2;
  float* C; int ldc; int K; int reluA; int reluC; int b2lim;
};
#define LDP 68
__global__ __launch_bounds__(256) void gemm_bt(GemmArgs g) {
  __shared__ float As[16][LDP];
  __shared__ float Ws[16][LDP];
  const int tid = threadIdx.x;
  const int tx = tid & 15, ty = tid >> 4;
  const int m0 = blockIdx.y * 64, n0 = blockIdx.x * 64;
  float acc[4][4] = {{0.f, 0.f, 0.f, 0.f}};
  const int K = g.K;
  for (int kb = 0; kb < K / 16; ++kb) {
    const int k0 = kb * 16;
#pragma unroll
    for (int i = 0; i < 4; ++i) {
      int idx = tid + i * 256;
      int ml = idx >> 4, kl = idx & 15;
      float a = g.A[(size_t)(m0 + ml) * K + k0 + kl];
      if (g.reluA) a = fmaxf(a, 0.f);
      As[kl][ml] = a;
      Ws[kl][ml] = g.W[(size_t)(n0 + ml) * K + k0 + kl];
    }
    __syncthreads();
#pragma unroll
    for (int k = 0; k < 16; ++k) {
      float4 av = *(const float4*)&As[k][ty * 4];
      float4 wv = *(const float4*)&Ws[k][tx * 4];
      float a[4] = {av.x, av.y, av.z, av.w};
      float w[4] = {wv.x, wv.y, wv.z, wv.w};
#pragma unroll
      for (int i = 0; i < 4; ++i)
#pragma unroll
        for (int j = 0; j < 4; ++j)
          acc[i][j] = fmaf(a[i], w[j], acc[i][j]);
    }
    __syncthreads();
  }
#pragma unroll
  for (int i = 0; i < 4; ++i) {
    int m = m0 + ty * 4 + i;
#pragma unroll
    for (int j = 0; j < 4; ++j) {
      int n = n0 + tx * 4 + j;
      float v = acc[i][j] + g.bias[n];
      if (g.bias2 && n < g.b2lim) v += g.bias2[n];
      if (g.reluC) v = fmaxf(v, 0.f);
      g.C[(size_t)m * g.ldc + n] = v;
    }
  }
}

// ============ one-time: duplicate init hidden into both layers' fp32 state bufs ============
__global__ __launch_bounds__(256) void copy2(const float* __restrict__ s,
                                             float* __restrict__ d0,
                                             float* __restrict__ d1) {
  int i = blockIdx.x * 256 + threadIdx.x;
  float v = s[i];
  d0[i] = v; d1[i] = v;
}

// init hidden -> frag blobs (both layers)
__global__ __launch_bounds__(256) void permute_frag(const float* __restrict__ s,
                                                    bf16* __restrict__ d0,
                                                    bf16* __restrict__ d1) {
  int g = blockIdx.x * 256 + threadIdx.x;      // (B/16)*32*64 groups
  int lane = g & 63, kc = (g >> 6) & 31, mt = g >> 11;
  int m = mt * 16 + (lane & 15), k = kc * 32 + ((lane >> 4) << 3);
  const float* src = s + (size_t)m * HDIM + k;
  s8v v;
#pragma unroll
  for (int j = 0; j < 8; ++j) v[j] = f2bs(src[j]);
  *(s8v*)((short*)d0 + (size_t)g * 8) = v;
  *(s8v*)((short*)d1 + (size_t)g * 8) = v;
}

// ============ the per-step fused kernel ============
// grid 208: blk 0..63 layer0(t=k) | 64..191 layer1(t=k-1) | 192..207 outproj(t=k-2)
// XCD stability: blk%8 == n-group%8 for every role -> per-XCD weight slice
// (~3.3 MB) stays L2-resident across the 258 launches.
struct StepArgs {
  int k;
  const int* target;
  const float* table;          // [V,3H] = relu(emb)@Wih0^T + b_ih0 + b_hh0(r,z only)
  const bf16* Whh0;            // frag blob, 3072 rows
  const float* bhh0n;          // b_hh0 + 2048
  const bf16* h0f_in; const float* h0l_in;   // h0l: natural [B][H] fp32
  bf16* h0f_out;      float* h0l_out;
  const bf16* Wih1; const bf16* Whh1;
  const float* bih1; const float* bhh1;
  const bf16* h1f_in; const float* h1l_in;   // H1[k-1]
  bf16* h1f_out;      float* h1l_out;        // H1[k]
  const bf16* Wof; const float* bo;
  float* out;
};

__global__ __launch_bounds__(256) void step_fused(StepArgs g) {
  __shared__ float smax[4][16];   // 256 B — cross-wave softmax exchange only
  __shared__ float ssum[4][16];   // 256 B
  const int blk = blockIdx.x;
  const int tid = threadIdx.x;
  const int w = tid >> 6, ln = tid & 63, l15 = ln & 15, quad = ln >> 4;

  if (blk < 64) {
    // ---- layer 0, t = k ----  block 64m x 64n, wave 32m x 32n x 3 gates
    if (g.k > 255) return;
    const int mg = blk >> 4, ng = blk & 15;      // blk%8 == ng%8 (XCD-stable)
    const int wy = w >> 1, wx = w & 1;
    const int mbase = mg * 64 + wy * 32;
    const int nbase = ng * 64 + wx * 32;
    const int MT0 = mbase >> 4;
    const int NT0 = nbase >> 4;
    // epilogue gathers hoisted: latency hides under the K-loop
    int ncol[2]; float bhn[2];
#pragma unroll
    for (int nj = 0; nj < 2; ++nj) {
      ncol[nj] = nbase + nj * 16 + l15;
      bhn[nj] = g.bhh0n[ncol[nj]];
    }
    float tr_[2][2][4], tz_[2][2][4], tn_[2][2][4], hp[2][2][4];
#pragma unroll
    for (int mi = 0; mi < 2; ++mi)
#pragma unroll
      for (int r = 0; r < 4; ++r) {
        const int m = ((MT0 + mi) << 4) + (quad << 2) + r;
        const int tok = (g.k == 0) ? 0 : g.target[m * TLEN + g.k - 1];
        const float* trow = g.table + (size_t)tok * H3;
#pragma unroll
        for (int nj = 0; nj < 2; ++nj) {
          const int n = ncol[nj];
          tr_[mi][nj][r] = trow[n];
          tz_[mi][nj][r] = trow[n + 1024];
          tn_[mi][nj][r] = trow[n + 2048];
          hp[mi][nj][r] = g.h0l_in[(size_t)m * HDIM + n];
        }
      }
    const bf16* pA0 = g.h0f_in + ((size_t)MT0 * 32) * 512 + ln * 8;
    const bf16* pB[3][2];
#pragma unroll
    for (int gi = 0; gi < 3; ++gi)
#pragma unroll
      for (int nj = 0; nj < 2; ++nj)
        pB[gi][nj] = g.Whh0 + ((size_t)((gi << 6) + NT0 + nj) * 32) * 512 + ln * 8;
    const f4v z4 = {0.f, 0.f, 0.f, 0.f};
    f4v acc[3][2][2];
#pragma unroll
    for (int gi = 0; gi < 3; ++gi)
#pragma unroll
      for (int mi = 0; mi < 2; ++mi)
#pragma unroll
        for (int nj = 0; nj < 2; ++nj) acc[gi][mi][nj] = z4;
#pragma unroll 4
    for (int kc = 0; kc < 32; ++kc) {
      s8v A0 = ld8(pA0 + kc * 512);
      s8v A1 = ld8(pA0 + (32 * 512) + kc * 512);
#pragma unroll
      for (int gi = 0; gi < 3; ++gi)
#pragma unroll
        for (int nj = 0; nj < 2; ++nj) {
          s8v B = ld8(pB[gi][nj] + kc * 512);
          acc[gi][0][nj] = mfma_bf16(A0, B, acc[gi][0][nj]);
          acc[gi][1][nj] = mfma_bf16(A1, B, acc[gi][1][nj]);
        }
    }
    const int kc2 = nbase >> 5;
#pragma unroll
    for (int mi = 0; mi < 2; ++mi) {
      const int MT = MT0 + mi;
      short* fo = (short*)g.h0f_out + (((size_t)(MT * 32 + kc2)) << 9) + (l15 & 7);
#pragma unroll
      for (int r = 0; r < 4; ++r) {
        const int m = (MT << 4) + (quad << 2) + r;
#pragma unroll
        for (int nj = 0; nj < 2; ++nj) {
          const int n = ncol[nj];
          float rr = sigf(tr_[mi][nj][r] + acc[0][mi][nj][r]);
          float zz = sigf(tz_[mi][nj][r] + acc[1][mi][nj][r]);
          float nn = tanhf(tn_[mi][nj][r] + rr * (acc[2][mi][nj][r] + bhn[nj]));
          float hv = (1.f - zz) * nn + zz * hp[mi][nj][r];
          g.h0l_out[(size_t)m * HDIM + n] = hv;
          const int lanep = (quad << 2) + r + (((nj << 1) + (l15 >> 3)) << 4);
          fo[lanep * 8] = f2bs(hv);
        }
      }
    }
  } else if (blk < 192) {
    // ---- layer 1, t = k-1 ----  block 64m x 32n, wave 32m x 16n
    if (g.k < 1 || g.k > 256) return;
    const int b1 = blk - 64;
    const int mg = b1 >> 5, ng = b1 & 31;        // blk%8 == ng%8 (XCD-stable)
    const int my = w >> 1, ny = w & 1;
    const int mbase = mg * 64 + my * 32;
    const int nbase = ng * 32 + ny * 16;
    const int MT0 = mbase >> 4;
    const int NT = nbase >> 4;
    const int n = nbase + l15;
    // hoisted gathers
    const float br = g.bih1[n] + g.bhh1[n];
    const float bz = g.bih1[n + 1024] + g.bhh1[n + 1024];
    const float bin = g.bih1[n + 2048], bhn = g.bhh1[n + 2048];
    float hp[2][4];
#pragma unroll
    for (int mi = 0; mi < 2; ++mi)
#pragma unroll
      for (int r = 0; r < 4; ++r) {
        const int m = ((MT0 + mi) << 4) + (quad << 2) + r;
        hp[mi][r] = g.h1l_in[(size_t)m * HDIM + n];
      }
    const bf16* pAx = g.h0f_in + ((size_t)MT0 * 32) * 512 + ln * 8;  // x = H0[k-1+1]... H0[t]
    const bf16* pAh = g.h1f_in + ((size_t)MT0 * 32) * 512 + ln * 8;
    const bf16* pI[3]; const bf16* pH[3];
#pragma unroll
    for (int gi = 0; gi < 3; ++gi) {
      pI[gi] = g.Wih1 + ((size_t)((gi << 6) + NT) * 32) * 512 + ln * 8;
      pH[gi] = g.Whh1 + ((size_t)((gi << 6) + NT) * 32) * 512 + ln * 8;
    }
    const f4v z4 = {0.f, 0.f, 0.f, 0.f};
    f4v ar[2] = {z4, z4}, az[2] = {z4, z4}, ain[2] = {z4, z4}, ahn[2] = {z4, z4};
#pragma unroll 2
    for (int kc = 0; kc < 32; ++kc) {
      s8v Ax0 = ld8(pAx + kc * 512);
      s8v Ax1 = ld8(pAx + (32 * 512) + kc * 512);
      s8v Ah0 = ld8(pAh + kc * 512);
      s8v Ah1 = ld8(pAh + (32 * 512) + kc * 512);
      s8v Bir = ld8(pI[0] + kc * 512);
      s8v Bhr = ld8(pH[0] + kc * 512);
      s8v Biz = ld8(pI[1] + kc * 512);
      s8v Bhz = ld8(pH[1] + kc * 512);
      s8v Bin = ld8(pI[2] + kc * 512);
      s8v Bhn = ld8(pH[2] + kc * 512);
      ar[0] = mfma_bf16(Ax0, Bir, ar[0]);  ar[0] = mfma_bf16(Ah0, Bhr, ar[0]);
      ar[1] = mfma_bf16(Ax1, Bir, ar[1]);  ar[1] = mfma_bf16(Ah1, Bhr, ar[1]);
      az[0] = mfma_bf16(Ax0, Biz, az[0]);  az[0] = mfma_bf16(Ah0, Bhz, az[0]);
      az[1] = mfma_bf16(Ax1, Biz, az[1]);  az[1] = mfma_bf16(Ah1, Bhz, az[1]);
      ain[0] = mfma_bf16(Ax0, Bin, ain[0]);
      ain[1] = mfma_bf16(Ax1, Bin, ain[1]);
      ahn[0] = mfma_bf16(Ah0, Bhn, ahn[0]);
      ahn[1] = mfma_bf16(Ah1, Bhn, ahn[1]);
    }
    const int lhigh = (ny << 1) + (l15 >> 3);
#pragma unroll
    for (int mi = 0; mi < 2; ++mi) {
      const int MT = MT0 + mi;
      short* fo = (short*)g.h1f_out + (((size_t)(MT * 32 + ng)) << 9) + (l15 & 7);
#pragma unroll
      for (int r = 0; r < 4; ++r) {
        const int m = (MT << 4) + (quad << 2) + r;
        float rr = sigf(ar[mi][r] + br);
        float zz = sigf(az[mi][r] + bz);
        float nn = tanhf(ain[mi][r] + bin + rr * (ahn[mi][r] + bhn));
        float hv = (1.f - zz) * nn + zz * hp[mi][r];
        g.h1l_out[(size_t)m * HDIM + n] = hv;
        fo[((quad << 2) + r + (lhigh << 4)) * 8] = f2bs(hv);
      }
    }
  } else {
    // ---- output projection + log_softmax, t = k-2 ----
    // 16 blocks x 16 rows; wave = 16m x 128n; logits register-resident
    if (g.k < 2) return;
    const int to = g.k - 2;
    const int blk2 = blk - 192;
    const int MT = blk2;
    const bf16* pA = g.h1f_in + ((size_t)MT * 32) * 512 + ln * 8;  // H1[k-1]
    float bov[8];
#pragma unroll
    for (int u = 0; u < 8; ++u) bov[u] = g.bo[(w << 7) + (u << 4) + l15];
    const f4v z4 = {0.f, 0.f, 0.f, 0.f};
    f4v acc[8];
#pragma unroll
    for (int u = 0; u < 8; ++u) acc[u] = z4;
#pragma unroll 2
    for (int kc = 0; kc < 32; ++kc) {
      s8v A = ld8(pA + kc * 512);
#pragma unroll
      for (int u = 0; u < 8; ++u) {
        s8v B = ld8(g.Wof + (((size_t)((w << 3) + u) * 32 + kc) << 9) + ln * 8);
        acc[u] = mfma_bf16(A, B, acc[u]);
      }
    }
    float lg[8][4];
#pragma unroll
    for (int u = 0; u < 8; ++u)
#pragma unroll
      for (int r = 0; r < 4; ++r) lg[u][r] = acc[u][r] + bov[u];
    // row max: per-lane over u, shfl over the 16-lane group, LDS across waves
    float mx[4];
#pragma unroll
    for (int r = 0; r < 4; ++r) {
      float m0 = lg[0][r];
#pragma unroll
      for (int u = 1; u < 8; ++u) m0 = fmaxf(m0, lg[u][r]);
#pragma unroll
      for (int o = 8; o > 0; o >>= 1) m0 = fmaxf(m0, __shfl_xor(m0, o));
      mx[r] = m0;
    }
    if (l15 == 0) {
#pragma unroll
      for (int r = 0; r < 4; ++r) smax[w][(quad << 2) + r] = mx[r];
    }
    __syncthreads();
    float rm[4];
#pragma unroll
    for (int r = 0; r < 4; ++r) {
      float m0 = smax[0][(quad << 2) + r];
#pragma unroll
      for (int ww = 1; ww < 4; ++ww) m0 = fmaxf(m0, smax[ww][(quad << 2) + r]);
      rm[r] = m0;
    }
    float sm[4];
#pragma unroll
    for (int r = 0; r < 4; ++r) {
      float s0 = 0.f;
#pragma unroll
      for (int u = 0; u < 8; ++u) s0 += expf(lg[u][r] - rm[r]);
#pragma unroll
      for (int o = 8; o > 0; o >>= 1) s0 += __shfl_xor(s0, o);
      sm[r] = s0;
    }
    if (l15 == 0) {
#pragma unroll
      for (int r = 0; r < 4; ++r) ssum[w][(quad << 2) + r] = sm[r];
    }
    __syncthreads();
#pragma unroll
    for (int r = 0; r < 4; ++r) {
      float s0 = ssum[0][(quad << 2) + r];
#pragma unroll
      for (int ww = 1; ww < 4; ++ww) s0 += ssum[ww][(quad << 2) + r];
      const float lse = rm[r] + logf(s0);
      const int m = (MT << 4) + (quad << 2) + r;
      float* orow = g.out + ((size_t)m * TLEN + to) * VDIM;
#pragma unroll
      for (int u = 0; u < 8; ++u) orow[(w << 7) + (u << 4) + l15] = lg[u][r] - lse;
    }
  }
}

// ============ final: h_final [2,B,H] (natural layout now -> plain concat copy) ============
__global__ __launch_bounds__(256) void unperm_hfinal(const float* __restrict__ h0l,
                                                     const float* __restrict__ h1l,
                                                     float* __restrict__ out) {
  int idx = blockIdx.x * 256 + threadIdx.x;   // 2*B*H
  const int BH = BATCH * HDIM;
  out[idx] = (idx < BH) ? h0l[idx] : h1l[idx - BH];
}

extern "C" void kernel_launch(void* const* d_in, const int* in_sizes, int n_in,
                              void* d_out, int out_size, void* d_ws, size_t ws_size,
                              hipStream_t stream) {
  const float* fps    = (const float*)d_in[1];
  const int* target   = (const int*)d_in[2];
  const float* emb    = (const float*)d_in[3];
  const float* Wc     = (const float*)d_in[4];
  const float* bc     = (const float*)d_in[5];
  const float* W_ih   = (const float*)d_in[6];   // [2,3H,H]
  const float* W_hh   = (const float*)d_in[7];
  const float* b_ih   = (const float*)d_in[8];
  const float* b_hh   = (const float*)d_in[9];
  const float* Wo     = (const float*)d_in[10];
  const float* bo     = (const float*)d_in[11];
  float* out = (float*)d_out;

  const int BH = BATCH * HDIM;
  const size_t WN = (size_t)H3 * HDIM;

  char* p = (char*)d_ws;
  float* hstd  = (float*)p; p += (size_t)BH * 4;
  float* table = (float*)p; p += (size_t)VDIM * H3 * 4;
  float* H0l[2]; H0l[0] = (float*)p; p += (size_t)BH * 4; H0l[1] = (float*)p; p += (size_t)BH * 4;
  float* H1l[2]; H1l[0] = (float*)p; p += (size_t)BH * 4; H1l[1] = (float*)p; p += (size_t)BH * 4;
  bf16* H0f[2]; H0f[0] = (bf16*)p; p += (size_t)BH * 2; H0f[1] = (bf16*)p; p += (size_t)BH * 2;
  bf16* H1f[2]; H1f[0] = (bf16*)p; p += (size_t)BH * 2; H1f[1] = (bf16*)p; p += (size_t)BH * 2;
  bf16* Whh0f = (bf16*)p; p += WN * 2;
  bf16* Wih1f = (bf16*)p; p += WN * 2;
  bf16* Whh1f = (bf16*)p; p += WN * 2;
  bf16* Wof   = (bf16*)p; p += (size_t)VDIM * HDIM * 2;

  // one-time weight shuffles into fragment blobs
  {
    int ng3 = (H3 / 16) * 32 * 64;             // 393216
    shuffle_w<<<ng3 / 256, 256, 0, stream>>>(W_hh, Whh0f, ng3);
    shuffle_w<<<ng3 / 256, 256, 0, stream>>>(W_ih + WN, Wih1f, ng3);
    shuffle_w<<<ng3 / 256, 256, 0, stream>>>(W_hh + WN, Whh1f, ng3);
    int ngv = (VDIM / 16) * 32 * 64;           // 65536
    shuffle_w<<<ngv / 256, 256, 0, stream>>>(Wo, Wof, ngv);
  }
  // init hidden: hstd = relu(fps @ Wc^T + bc)
  {
    GemmArgs a; a.A = fps; a.W = Wc; a.bias = bc; a.bias2 = nullptr;
    a.C = hstd; a.ldc = HDIM; a.K = FPDIM; a.reluA = 0; a.reluC = 1; a.b2lim = 0;
    gemm_bt<<<dim3(HDIM / 64, BATCH / 64), 256, 0, stream>>>(a);
  }
  // gi0 table = relu(emb) @ Wih0^T + b_ih0 + b_hh0 (r,z parts only)
  {
    GemmArgs a; a.A = emb; a.W = W_ih; a.bias = b_ih; a.bias2 = b_hh;
    a.C = table; a.ldc = H3; a.K = HDIM; a.reluA = 1; a.reluC = 0; a.b2lim = 2048;
    gemm_bt<<<dim3(H3 / 64, VDIM / 64), 256, 0, stream>>>(a);
  }
  // init hidden into fp32 state (natural layout) + frag blobs (parity-0 buffers)
  copy2<<<BH / 256, 256, 0, stream>>>(hstd, H0l[0], H1l[0]);
  permute_frag<<<(BATCH / 16) * 32 * 64 / 256, 256, 0, stream>>>(hstd, H0f[0], H1f[0]);

  // pipelined step loop: launch k does layer0(k) | layer1(k-1) | outproj(k-2)
  for (int k = 0; k <= TLEN + 1; ++k) {
    StepArgs s;
    s.k = k; s.target = target; s.table = table;
    s.Whh0 = Whh0f; s.bhh0n = b_hh + 2048;
    s.h0f_in = H0f[k & 1];         s.h0l_in = H0l[k & 1];
    s.h0f_out = H0f[(k + 1) & 1];  s.h0l_out = H0l[(k + 1) & 1];
    s.Wih1 = Wih1f; s.Whh1 = Whh1f;
    s.bih1 = b_ih + H3; s.bhh1 = b_hh + H3;
    s.h1f_in = H1f[(k + 1) & 1];   s.h1l_in = H1l[(k + 1) & 1];  // H1[k-1]
    s.h1f_out = H1f[k & 1];        s.h1l_out = H1l[k & 1];        // H1[k]
    s.Wof = Wof; s.bo = bo; s.out = out;
    step_fused<<<208, 256, 0, stream>>>(s);
  }

  // h_final = [H0[256], H1[256]] (both land in parity-0 buffers)
  unperm_hfinal<<<2 * BH / 256, 256, 0, stream>>>(H0l[0], H1l[0],
                                                  out + (size_t)BATCH * TLEN * VDIM);
}